// Round 13
// baseline (364.582 us; speedup 1.0000x reference)
//
#include <hip/hip_runtime.h>
#include <math.h>

#define B 64
#define Lw 2048
#define Hd 1024
#define Vd 50257

// ws offsets (in floats)
#define WS_CATB   0          // bf16 pack [256][64][8]: h1(kb 0..127), ctx(128..255) = 65536 f
#define WS_ENERGY 65536      // energies [64][2048] = 131072
#define WS_PART   196608     // 32*64 partials * 1032 = 2113536
#define WS_CONC   2310144    // concat_out bf16 pack [128][64][8] = 32768 f

// d_out offsets (floats): output[B][V], h1[1][B][H], c1[1][B][H], attn[B][1][L]
#define OUT_H1   3216448
#define OUT_C1   3281984
#define OUT_ATTN 3347520

#define NCHUNK 32
#define LCHUNK 64
#define PSTRIDE 1032

// DIAGNOSTIC: repeat attn_part body 3x inside one dispatch so it exceeds the
// harness poison-fill durations (~320us) and surfaces in rocprof top-5 with
// its PMC row. Each rep recomputes and rewrites IDENTICAL values ->
// deterministic, graph-replay-safe.
#define ATTN_REPS 3

typedef __bf16 bf16x8 __attribute__((ext_vector_type(8)));
typedef float f32x4 __attribute__((ext_vector_type(4)));

__device__ __forceinline__ float sigm(float x) { return 1.f / (1.f + expf(-x)); }

#define CVT8(dst, w0, w1)                                            \
    dst[0] = (__bf16)w0.x; dst[1] = (__bf16)w0.y;                    \
    dst[2] = (__bf16)w0.z; dst[3] = (__bf16)w0.w;                    \
    dst[4] = (__bf16)w1.x; dst[5] = (__bf16)w1.y;                    \
    dst[6] = (__bf16)w1.z; dst[7] = (__bf16)w1.w;

// ---------------- fused embed + gates(MFMA, 8-wave K-split) + LSTM pointwise
__global__ void k_gates_lstm(const int* __restrict__ seq,
                             const float* __restrict__ emb, const float* __restrict__ h0,
                             const float* __restrict__ W_ih, const float* __restrict__ W_hh,
                             const float* __restrict__ b_ih, const float* __restrict__ b_hh,
                             const float* __restrict__ c0,
                             float* __restrict__ h1o, float* __restrict__ c1o,
                             __bf16* __restrict__ catb)
{
    __shared__ float lds[8][64][20];
    __shared__ float gsum[16][66];

    int wave = threadIdx.x >> 6, lane = threadIdx.x & 63;
    int hh0 = blockIdx.x * 4;
    int rloc = lane & 15;                      // local row: gate g, hh offset
    int wrow = (rloc >> 2) * Hd + hh0 + (rloc & 3);
    int kq = lane >> 4;
    int isH = wave >> 2;
    int kbase = (wave & 3) * 256;

    const float* wp = (isH ? W_hh : W_ih) + (size_t)wrow * Hd + kbase + kq * 8;

    f32x4 acc[4] = {{0.f,0.f,0.f,0.f},{0.f,0.f,0.f,0.f},
                    {0.f,0.f,0.f,0.f},{0.f,0.f,0.f,0.f}};

    if (!isH) {
        int tok[4];
#pragma unroll
        for (int mt = 0; mt < 4; ++mt) tok[mt] = seq[mt * 16 + rloc];
#pragma unroll 2
        for (int k0 = 0; k0 < 256; k0 += 32) {
            float4 w0 = *(const float4*)(wp + k0);
            float4 w1 = *(const float4*)(wp + k0 + 4);
            bf16x8 bf; CVT8(bf, w0, w1);
#pragma unroll
            for (int mt = 0; mt < 4; ++mt) {
                const float* xp = emb + (size_t)tok[mt] * Hd + kbase + k0 + kq * 8;
                float4 a0 = *(const float4*)xp;
                float4 a1 = *(const float4*)(xp + 4);
                bf16x8 af; CVT8(af, a0, a1);
                acc[mt] = __builtin_amdgcn_mfma_f32_16x16x32_bf16(af, bf, acc[mt], 0, 0, 0);
            }
        }
    } else {
#pragma unroll 2
        for (int k0 = 0; k0 < 256; k0 += 32) {
            float4 w0 = *(const float4*)(wp + k0);
            float4 w1 = *(const float4*)(wp + k0 + 4);
            bf16x8 bhi, blo;
            {
                float wf[8] = {w0.x, w0.y, w0.z, w0.w, w1.x, w1.y, w1.z, w1.w};
#pragma unroll
                for (int i = 0; i < 8; ++i) {
                    __bf16 hi = (__bf16)wf[i];
                    bhi[i] = hi;
                    blo[i] = (__bf16)(wf[i] - (float)hi);
                }
            }
#pragma unroll
            for (int mt = 0; mt < 4; ++mt) {
                const float* hp = h0 + (size_t)(mt * 16 + rloc) * Hd + kbase + k0 + kq * 8;
                float4 a0 = *(const float4*)hp;
                float4 a1 = *(const float4*)(hp + 4);
                float hf[8] = {a0.x, a0.y, a0.z, a0.w, a1.x, a1.y, a1.z, a1.w};
                bf16x8 ahi, alo;
#pragma unroll
                for (int i = 0; i < 8; ++i) {
                    __bf16 hi = (__bf16)hf[i];
                    ahi[i] = hi;
                    alo[i] = (__bf16)(hf[i] - (float)hi);
                }
                acc[mt] = __builtin_amdgcn_mfma_f32_16x16x32_bf16(ahi, bhi, acc[mt], 0, 0, 0);
                acc[mt] = __builtin_amdgcn_mfma_f32_16x16x32_bf16(ahi, blo, acc[mt], 0, 0, 0);
                acc[mt] = __builtin_amdgcn_mfma_f32_16x16x32_bf16(alo, bhi, acc[mt], 0, 0, 0);
            }
        }
    }

#pragma unroll
    for (int mt = 0; mt < 4; ++mt)
        *(f32x4*)&lds[wave][lane][mt * 4] = acc[mt];
    __syncthreads();

    if (wave < 4) {
        int mt = wave;
        float bv = b_ih[wrow] + b_hh[wrow];
#pragma unroll
        for (int r = 0; r < 4; ++r) {
            float s = 0.f;
#pragma unroll
            for (int w = 0; w < 8; ++w) s += lds[w][lane][mt * 4 + r];
            int m = mt * 16 + kq * 4 + r;       // batch
            gsum[rloc][m] = s + bv;
        }
    }
    __syncthreads();

    int t = threadIdx.x;
    if (t < 256) {
        int b = t & 63, hl = t >> 6;
        int hh = hh0 + hl;
        float gi = gsum[0 + hl][b];
        float gf = gsum[4 + hl][b];
        float gg = gsum[8 + hl][b];
        float go = gsum[12 + hl][b];
        float c  = c0[(size_t)b * Hd + hh];
        float c1 = sigm(gf) * c + sigm(gi) * tanhf(gg);
        float h1 = sigm(go) * tanhf(c1);
        h1o[(size_t)b * Hd + hh] = h1;
        c1o[(size_t)b * Hd + hh] = c1;
        catb[(size_t)(hh >> 3) * 512 + b * 8 + (hh & 7)] = (__bf16)h1;
    }
}

// ---------------- fused energies + online-softmax context partials (one enc pass)
// r11-proven body, repeated ATTN_REPS times for diagnostic visibility.
__global__ void k_attn_part(const float* __restrict__ enc, const float* __restrict__ h1,
                            float* __restrict__ energy, float* __restrict__ part)
{
    int chunk = blockIdx.x, b = blockIdx.y;
    int wave = threadIdx.x >> 6, lane = threadIdx.x & 63;

    float4 qv[4];
#pragma unroll
    for (int q = 0; q < 4; ++q)
        qv[q] = *(const float4*)(h1 + (size_t)b * Hd + q * 256 + lane * 4);

    __shared__ float lctx[4][Hd];
    __shared__ float lms[4][2];

#pragma unroll 1
    for (int rep = 0; rep < ATTN_REPS; ++rep) {
        float4 ctx[4];
#pragma unroll
        for (int q = 0; q < 4; ++q) ctx[q] = make_float4(0.f, 0.f, 0.f, 0.f);
        float m = -INFINITY, s = 0.f;

        for (int i = 0; i < LCHUNK / 8; ++i) {
            int l = chunk * LCHUNK + i * 8 + wave * 2;
            const float* ep0 = enc + ((size_t)l * B + b) * Hd + lane * 4;
            const float* ep1 = ep0 + (size_t)B * Hd;
            float4 ev0[4], ev1[4];
#pragma unroll
            for (int q = 0; q < 4; ++q) {
                ev0[q] = *(const float4*)(ep0 + q * 256);
                ev1[q] = *(const float4*)(ep1 + q * 256);
            }
            float d0 = 0.f, d1 = 0.f;
#pragma unroll
            for (int q = 0; q < 4; ++q) {
                d0 += ev0[q].x * qv[q].x + ev0[q].y * qv[q].y
                    + ev0[q].z * qv[q].z + ev0[q].w * qv[q].w;
                d1 += ev1[q].x * qv[q].x + ev1[q].y * qv[q].y
                    + ev1[q].z * qv[q].z + ev1[q].w * qv[q].w;
            }
#pragma unroll
            for (int off = 32; off >= 1; off >>= 1) {
                d0 += __shfl_xor(d0, off);
                d1 += __shfl_xor(d1, off);
            }
            if (lane == 0) {
                energy[(size_t)b * Lw + l] = d0;
                energy[(size_t)b * Lw + l + 1] = d1;
            }

            float mn = fmaxf(d0, d1);
            if (mn > m) {                          // wave-uniform
                float sc = expf(m - mn);
                s *= sc;
#pragma unroll
                for (int q = 0; q < 4; ++q) {
                    ctx[q].x *= sc; ctx[q].y *= sc; ctx[q].z *= sc; ctx[q].w *= sc;
                }
                m = mn;
            }
            float w0 = expf(d0 - m), w1 = expf(d1 - m);
            s += w0 + w1;
#pragma unroll
            for (int q = 0; q < 4; ++q) {
                ctx[q].x += w0 * ev0[q].x + w1 * ev1[q].x;
                ctx[q].y += w0 * ev0[q].y + w1 * ev1[q].y;
                ctx[q].z += w0 * ev0[q].z + w1 * ev1[q].z;
                ctx[q].w += w0 * ev0[q].w + w1 * ev1[q].w;
            }
        }

        // combine the 4 waves of this block
#pragma unroll
        for (int q = 0; q < 4; ++q)
            *(float4*)(&lctx[wave][q * 256 + lane * 4]) = ctx[q];
        if (lane == 0) { lms[wave][0] = m; lms[wave][1] = s; }
        __syncthreads();

        float mb = fmaxf(fmaxf(lms[0][0], lms[1][0]), fmaxf(lms[2][0], lms[3][0]));
        float sc0 = expf(lms[0][0] - mb), sc1 = expf(lms[1][0] - mb);
        float sc2 = expf(lms[2][0] - mb), sc3 = expf(lms[3][0] - mb);
        float sb = lms[0][1] * sc0 + lms[1][1] * sc1 + lms[2][1] * sc2 + lms[3][1] * sc3;

        int t = threadIdx.x;
        float* pb = part + (size_t)(chunk * B + b) * PSTRIDE;
        float4 a0 = *(float4*)(&lctx[0][t * 4]);
        float4 a1 = *(float4*)(&lctx[1][t * 4]);
        float4 a2 = *(float4*)(&lctx[2][t * 4]);
        float4 a3 = *(float4*)(&lctx[3][t * 4]);
        float4 v;
        v.x = a0.x * sc0 + a1.x * sc1 + a2.x * sc2 + a3.x * sc3;
        v.y = a0.y * sc0 + a1.y * sc1 + a2.y * sc2 + a3.y * sc3;
        v.z = a0.z * sc0 + a1.z * sc1 + a2.z * sc2 + a3.z * sc3;
        v.w = a0.w * sc0 + a1.w * sc1 + a2.w * sc2 + a3.w * sc3;
        *(float4*)(pb + t * 4) = v;
        if (t == 0) { pb[1024] = mb; pb[1025] = sb; }
        __syncthreads();   // protect lctx/lms reuse in next rep
    }
}

// ---------------- merge partials -> ctx (bf16 pack) + attn output normalize
__global__ void k_attn_combine(const float* __restrict__ part,
                               const float* __restrict__ energy,
                               __bf16* __restrict__ catb, float* __restrict__ attn)
{
    int b = blockIdx.x, t = threadIdx.x;
    float m = -INFINITY;
#pragma unroll
    for (int c = 0; c < NCHUNK; ++c)
        m = fmaxf(m, part[(size_t)(c * B + b) * PSTRIDE + 1024]);
    float s = 0.f, scl[NCHUNK];
#pragma unroll
    for (int c = 0; c < NCHUNK; ++c) {
        const float* pb = part + (size_t)(c * B + b) * PSTRIDE;
        scl[c] = expf(pb[1024] - m);
        s += pb[1025] * scl[c];
    }
    float4 v = make_float4(0.f, 0.f, 0.f, 0.f);
#pragma unroll
    for (int c = 0; c < NCHUNK; ++c) {
        float4 p = *(const float4*)(part + (size_t)(c * B + b) * PSTRIDE + t * 4);
        v.x += p.x * scl[c]; v.y += p.y * scl[c]; v.z += p.z * scl[c]; v.w += p.w * scl[c];
    }
    float inv = 1.f / s;
    v.x *= inv; v.y *= inv; v.z *= inv; v.w *= inv;
    int k = 1024 + t * 4;                                   // ctx k index
    __bf16* cp = catb + (size_t)(k >> 3) * 512 + b * 8 + (k & 7);
    cp[0] = (__bf16)v.x; cp[1] = (__bf16)v.y;
    cp[2] = (__bf16)v.z; cp[3] = (__bf16)v.w;

#pragma unroll
    for (int j = 0; j < 8; ++j) {
        int l = t + j * 256;
        attn[(size_t)b * Lw + l] = expf(energy[(size_t)b * Lw + l] - m) * inv;
    }
}

// ---------------- concat_out via bf16 MFMA, K-split over 8 waves (LDS reduce)
__global__ void k_concat_mfma(const __bf16* __restrict__ catb,
                              const float* __restrict__ W, const float* __restrict__ bias,
                              __bf16* __restrict__ conc)
{
    __shared__ float lds[8][64][20];
    int wave = threadIdx.x >> 6, lane = threadIdx.x & 63;
    int n0 = blockIdx.x * 16;
    int nl = n0 + (lane & 15);
    int kq = lane >> 4;
    int kbase = wave * 256;            // 8 waves x 256 = K=2048

    const float* wp = W + (size_t)nl * (2 * Hd) + kbase + kq * 8;
    const __bf16* ap = catb + (lane & 15) * 8;

    f32x4 acc[4] = {{0.f,0.f,0.f,0.f},{0.f,0.f,0.f,0.f},
                    {0.f,0.f,0.f,0.f},{0.f,0.f,0.f,0.f}};

#pragma unroll 4
    for (int k0 = 0; k0 < 256; k0 += 32) {
        float4 w0 = *(const float4*)(wp + k0);
        float4 w1 = *(const float4*)(wp + k0 + 4);
        bf16x8 bf; CVT8(bf, w0, w1);
        int kb = ((kbase + k0) >> 3) + kq;
#pragma unroll
        for (int mt = 0; mt < 4; ++mt) {
            bf16x8 a = *(const bf16x8*)(ap + (size_t)kb * 512 + mt * 128);
            acc[mt] = __builtin_amdgcn_mfma_f32_16x16x32_bf16(a, bf, acc[mt], 0, 0, 0);
        }
    }

#pragma unroll
    for (int mt = 0; mt < 4; ++mt)
        *(f32x4*)&lds[wave][lane][mt * 4] = acc[mt];
    __syncthreads();

    if (wave < 4) {
        int mt = wave;
        float bv = bias[nl];
#pragma unroll
        for (int r = 0; r < 4; ++r) {
            float s = 0.f;
#pragma unroll
            for (int w = 0; w < 8; ++w) s += lds[w][lane][mt * 4 + r];
            int m = mt * 16 + kq * 4 + r;       // batch
            conc[(size_t)(nl >> 3) * 512 + m * 8 + (nl & 7)] = (__bf16)tanhf(s + bv);
        }
    }
}

// ---------------- vocab projection via bf16 MFMA 16x16x32
__global__ void k_vocab_mfma(const __bf16* __restrict__ apack,
                             const float* __restrict__ W,
                             const float* __restrict__ bias,
                             float* __restrict__ out)
{
    int wave = threadIdx.x >> 6;
    int lane = threadIdx.x & 63;
    int n0 = (blockIdx.x * 2 + wave) * 16;
    if (n0 > Vd - 16) n0 = Vd - 16;        // tail shift-down (dup writes benign)

    int nl = n0 + (lane & 15);
    int kq = lane >> 4;
    const float* wp = W + (size_t)nl * Hd + kq * 8;
    const __bf16* ap = apack + (size_t)(lane & 15) * 8;

    f32x4 acc[4] = {{0.f,0.f,0.f,0.f},{0.f,0.f,0.f,0.f},
                    {0.f,0.f,0.f,0.f},{0.f,0.f,0.f,0.f}};

    float4 c0 = *(const float4*)(wp + 0);
    float4 c1 = *(const float4*)(wp + 4);
    float4 c2 = *(const float4*)(wp + 32);
    float4 c3 = *(const float4*)(wp + 36);

#pragma unroll 2
    for (int k0 = 0; k0 < Hd; k0 += 64) {
        int kn = (k0 + 64 < Hd) ? (k0 + 64) : k0;      // clamp: last prefetch unused
        float4 p0 = *(const float4*)(wp + kn);
        float4 p1 = *(const float4*)(wp + kn + 4);
        float4 p2 = *(const float4*)(wp + kn + 32);
        float4 p3 = *(const float4*)(wp + kn + 36);

        bf16x8 bf0; CVT8(bf0, c0, c1);
        bf16x8 bf1; CVT8(bf1, c2, c3);
        int kb0 = (k0 >> 3) + kq, kb1 = kb0 + 4;
#pragma unroll
        for (int mt = 0; mt < 4; ++mt) {
            bf16x8 a0 = *(const bf16x8*)(ap + (size_t)kb0 * 512 + mt * 128);
            acc[mt] = __builtin_amdgcn_mfma_f32_16x16x32_bf16(a0, bf0, acc[mt], 0, 0, 0);
        }
#pragma unroll
        for (int mt = 0; mt < 4; ++mt) {
            bf16x8 a1 = *(const bf16x8*)(ap + (size_t)kb1 * 512 + mt * 128);
            acc[mt] = __builtin_amdgcn_mfma_f32_16x16x32_bf16(a1, bf1, acc[mt], 0, 0, 0);
        }
        c0 = p0; c1 = p1; c2 = p2; c3 = p3;
    }

    float bv = bias[nl];
#pragma unroll
    for (int mt = 0; mt < 4; ++mt)
#pragma unroll
        for (int r = 0; r < 4; ++r) {
            int m = mt * 16 + (lane >> 4) * 4 + r;   // batch (C/D row)
            out[(size_t)m * Vd + nl] = acc[mt][r] + bv;
        }
}

extern "C" void kernel_launch(void* const* d_in, const int* in_sizes, int n_in,
                              void* d_out, int out_size, void* d_ws, size_t ws_size,
                              hipStream_t stream)
{
    const int*   seq    = (const int*)d_in[0];
    const float* enc    = (const float*)d_in[1];
    const float* h0     = (const float*)d_in[2];
    const float* c0     = (const float*)d_in[3];
    const float* emb    = (const float*)d_in[4];
    const float* W_ih   = (const float*)d_in[5];
    const float* W_hh   = (const float*)d_in[6];
    const float* b_ih   = (const float*)d_in[7];
    const float* b_hh   = (const float*)d_in[8];
    const float* W_cat  = (const float*)d_in[9];
    const float* b_cat  = (const float*)d_in[10];
    const float* W_out  = (const float*)d_in[11];
    const float* b_out  = (const float*)d_in[12];
    float* out = (float*)d_out;
    float* ws  = (float*)d_ws;

    __bf16* catb   = (__bf16*)(ws + WS_CATB);
    float*  energy = ws + WS_ENERGY;
    float*  part   = ws + WS_PART;
    __bf16* conc   = (__bf16*)(ws + WS_CONC);

    // fused embed+gates+LSTM: 256 blocks (4 hh each) x 512 threads
    k_gates_lstm<<<256, 512, 0, stream>>>(seq, emb, h0, W_ih, W_hh, b_ih, b_hh, c0,
                                          out + OUT_H1, out + OUT_C1, catb);
    // energies + online-softmax partials (x ATTN_REPS diagnostic)
    k_attn_part<<<dim3(NCHUNK, B), 256, 0, stream>>>(enc, out + OUT_H1, energy, part);
    // merge partials + attn normalize: 64 blocks x 256 threads
    k_attn_combine<<<B, 256, 0, stream>>>(part, energy, catb, out + OUT_ATTN);
    // concat: 64 blocks x 512 threads (8-way K-split)
    k_concat_mfma<<<64, 512, 0, stream>>>(catb, W_cat, b_cat, conc);
    // vocab: 1571 blocks x 128 threads
    k_vocab_mfma<<<1571, 128, 0, stream>>>(conc, W_out, b_out, out);
}

// Round 14
// 259.116 us; speedup vs baseline: 1.4070x; 1.4070x over previous
//
#include <hip/hip_runtime.h>
#include <math.h>

#define B 64
#define Lw 2048
#define Hd 1024
#define Vd 50257

// attn geometry: block = 8 waves x 2 b = 16 consecutive b; 64KB contiguous/l
#define LCB 16                  // l rows per block
#define NLCHUNK (Lw / LCB)      // 128 chunks
#define BGRP 16                 // b per block
#define PSTRIDE 1032

// ws offsets (in floats)
#define WS_CATB   0          // bf16 pack [256][64][8]: h1(kb 0..127), ctx(128..255) = 65536 f
#define WS_ENERGY 65536      // energies [64][2048] = 131072
#define WS_PART   196608     // 128*64 partials * 1032 = 8454144
#define WS_CONC   8650752    // concat_out bf16 pack [128][64][8] = 32768 f

// d_out offsets (floats): output[B][V], h1[1][B][H], c1[1][B][H], attn[B][1][L]
#define OUT_H1   3216448
#define OUT_C1   3281984
#define OUT_ATTN 3347520

typedef __bf16 bf16x8 __attribute__((ext_vector_type(8)));
typedef float f32x4 __attribute__((ext_vector_type(4)));

__device__ __forceinline__ float sigm(float x) { return 1.f / (1.f + expf(-x)); }

#define CVT8(dst, w0, w1)                                            \
    dst[0] = (__bf16)w0.x; dst[1] = (__bf16)w0.y;                    \
    dst[2] = (__bf16)w0.z; dst[3] = (__bf16)w0.w;                    \
    dst[4] = (__bf16)w1.x; dst[5] = (__bf16)w1.y;                    \
    dst[6] = (__bf16)w1.z; dst[7] = (__bf16)w1.w;

// ---------------- fused embed + gates(MFMA, 8-wave K-split) + LSTM pointwise
__global__ void k_gates_lstm(const int* __restrict__ seq,
                             const float* __restrict__ emb, const float* __restrict__ h0,
                             const float* __restrict__ W_ih, const float* __restrict__ W_hh,
                             const float* __restrict__ b_ih, const float* __restrict__ b_hh,
                             const float* __restrict__ c0,
                             float* __restrict__ h1o, float* __restrict__ c1o,
                             __bf16* __restrict__ catb)
{
    __shared__ float lds[8][64][20];
    __shared__ float gsum[16][66];

    int wave = threadIdx.x >> 6, lane = threadIdx.x & 63;
    int hh0 = blockIdx.x * 4;
    int rloc = lane & 15;                      // local row: gate g, hh offset
    int wrow = (rloc >> 2) * Hd + hh0 + (rloc & 3);
    int kq = lane >> 4;
    int isH = wave >> 2;
    int kbase = (wave & 3) * 256;

    const float* wp = (isH ? W_hh : W_ih) + (size_t)wrow * Hd + kbase + kq * 8;

    f32x4 acc[4] = {{0.f,0.f,0.f,0.f},{0.f,0.f,0.f,0.f},
                    {0.f,0.f,0.f,0.f},{0.f,0.f,0.f,0.f}};

    if (!isH) {
        int tok[4];
#pragma unroll
        for (int mt = 0; mt < 4; ++mt) tok[mt] = seq[mt * 16 + rloc];
#pragma unroll 2
        for (int k0 = 0; k0 < 256; k0 += 32) {
            float4 w0 = *(const float4*)(wp + k0);
            float4 w1 = *(const float4*)(wp + k0 + 4);
            bf16x8 bf; CVT8(bf, w0, w1);
#pragma unroll
            for (int mt = 0; mt < 4; ++mt) {
                const float* xp = emb + (size_t)tok[mt] * Hd + kbase + k0 + kq * 8;
                float4 a0 = *(const float4*)xp;
                float4 a1 = *(const float4*)(xp + 4);
                bf16x8 af; CVT8(af, a0, a1);
                acc[mt] = __builtin_amdgcn_mfma_f32_16x16x32_bf16(af, bf, acc[mt], 0, 0, 0);
            }
        }
    } else {
#pragma unroll 2
        for (int k0 = 0; k0 < 256; k0 += 32) {
            float4 w0 = *(const float4*)(wp + k0);
            float4 w1 = *(const float4*)(wp + k0 + 4);
            bf16x8 bhi, blo;
            {
                float wf[8] = {w0.x, w0.y, w0.z, w0.w, w1.x, w1.y, w1.z, w1.w};
#pragma unroll
                for (int i = 0; i < 8; ++i) {
                    __bf16 hi = (__bf16)wf[i];
                    bhi[i] = hi;
                    blo[i] = (__bf16)(wf[i] - (float)hi);
                }
            }
#pragma unroll
            for (int mt = 0; mt < 4; ++mt) {
                const float* hp = h0 + (size_t)(mt * 16 + rloc) * Hd + kbase + k0 + kq * 8;
                float4 a0 = *(const float4*)hp;
                float4 a1 = *(const float4*)(hp + 4);
                float hf[8] = {a0.x, a0.y, a0.z, a0.w, a1.x, a1.y, a1.z, a1.w};
                bf16x8 ahi, alo;
#pragma unroll
                for (int i = 0; i < 8; ++i) {
                    __bf16 hi = (__bf16)hf[i];
                    ahi[i] = hi;
                    alo[i] = (__bf16)(hf[i] - (float)hi);
                }
                acc[mt] = __builtin_amdgcn_mfma_f32_16x16x32_bf16(ahi, bhi, acc[mt], 0, 0, 0);
                acc[mt] = __builtin_amdgcn_mfma_f32_16x16x32_bf16(ahi, blo, acc[mt], 0, 0, 0);
                acc[mt] = __builtin_amdgcn_mfma_f32_16x16x32_bf16(alo, bhi, acc[mt], 0, 0, 0);
            }
        }
    }

#pragma unroll
    for (int mt = 0; mt < 4; ++mt)
        *(f32x4*)&lds[wave][lane][mt * 4] = acc[mt];
    __syncthreads();

    if (wave < 4) {
        int mt = wave;
        float bv = b_ih[wrow] + b_hh[wrow];
#pragma unroll
        for (int r = 0; r < 4; ++r) {
            float s = 0.f;
#pragma unroll
            for (int w = 0; w < 8; ++w) s += lds[w][lane][mt * 4 + r];
            int m = mt * 16 + kq * 4 + r;       // batch
            gsum[rloc][m] = s + bv;
        }
    }
    __syncthreads();

    int t = threadIdx.x;
    if (t < 256) {
        int b = t & 63, hl = t >> 6;
        int hh = hh0 + hl;
        float gi = gsum[0 + hl][b];
        float gf = gsum[4 + hl][b];
        float gg = gsum[8 + hl][b];
        float go = gsum[12 + hl][b];
        float c  = c0[(size_t)b * Hd + hh];
        float c1 = sigm(gf) * c + sigm(gi) * tanhf(gg);
        float h1 = sigm(go) * tanhf(c1);
        h1o[(size_t)b * Hd + hh] = h1;
        c1o[(size_t)b * Hd + hh] = c1;
        catb[(size_t)(hh >> 3) * 512 + b * 8 + (hh & 7)] = (__bf16)h1;
    }
}

// ---------------- energies + online-softmax context partials, b-contiguous layout
// Block = (lchunk, bgroup): 8 waves, wave owns b0=bg*16+w*2 and b0+1.
// Per l, the block reads enc[l][bg*16 .. +16][:] = 64KB CONTIGUOUS (vs 4KB
// scattered before) -> cold-HBM streaming efficiency. No cross-wave combine.
__global__ void __launch_bounds__(512, 4)
k_attn_part(const float* __restrict__ enc, const float* __restrict__ h1,
            float* __restrict__ energy, float* __restrict__ part)
{
    int lc = blockIdx.x, bg = blockIdx.y;
    int wave = threadIdx.x >> 6, lane = threadIdx.x & 63;
    int b0 = bg * BGRP + wave * 2;
    int b1 = b0 + 1;

    float4 qv0[4], qv1[4], ctx0[4], ctx1[4];
#pragma unroll
    for (int q = 0; q < 4; ++q) {
        qv0[q] = *(const float4*)(h1 + (size_t)b0 * Hd + q * 256 + lane * 4);
        qv1[q] = *(const float4*)(h1 + (size_t)b1 * Hd + q * 256 + lane * 4);
        ctx0[q] = make_float4(0.f, 0.f, 0.f, 0.f);
        ctx1[q] = make_float4(0.f, 0.f, 0.f, 0.f);
    }
    float m0 = -INFINITY, s0 = 0.f, m1 = -INFINITY, s1 = 0.f;

    for (int i = 0; i < LCB; ++i) {
        int l = lc * LCB + i;
        const float* e0 = enc + ((size_t)l * B + b0) * Hd + lane * 4;
        const float* e1 = e0 + Hd;
        float4 ev0[4], ev1[4];
#pragma unroll
        for (int q = 0; q < 4; ++q) {
            ev0[q] = *(const float4*)(e0 + q * 256);
            ev1[q] = *(const float4*)(e1 + q * 256);
        }
        float d0 = 0.f, d1 = 0.f;
#pragma unroll
        for (int q = 0; q < 4; ++q) {
            d0 += ev0[q].x * qv0[q].x + ev0[q].y * qv0[q].y
                + ev0[q].z * qv0[q].z + ev0[q].w * qv0[q].w;
            d1 += ev1[q].x * qv1[q].x + ev1[q].y * qv1[q].y
                + ev1[q].z * qv1[q].z + ev1[q].w * qv1[q].w;
        }
#pragma unroll
        for (int off = 32; off >= 1; off >>= 1) {
            d0 += __shfl_xor(d0, off);
            d1 += __shfl_xor(d1, off);
        }
        if (lane == 0) {
            energy[(size_t)b0 * Lw + l] = d0;
            energy[(size_t)b1 * Lw + l] = d1;
        }

        if (d0 > m0) {                         // wave-uniform
            float sc = expf(m0 - d0);
            s0 *= sc;
#pragma unroll
            for (int q = 0; q < 4; ++q) {
                ctx0[q].x *= sc; ctx0[q].y *= sc; ctx0[q].z *= sc; ctx0[q].w *= sc;
            }
            m0 = d0;
        }
        float w0 = expf(d0 - m0);
        s0 += w0;
#pragma unroll
        for (int q = 0; q < 4; ++q) {
            ctx0[q].x += w0 * ev0[q].x; ctx0[q].y += w0 * ev0[q].y;
            ctx0[q].z += w0 * ev0[q].z; ctx0[q].w += w0 * ev0[q].w;
        }

        if (d1 > m1) {                         // wave-uniform
            float sc = expf(m1 - d1);
            s1 *= sc;
#pragma unroll
            for (int q = 0; q < 4; ++q) {
                ctx1[q].x *= sc; ctx1[q].y *= sc; ctx1[q].z *= sc; ctx1[q].w *= sc;
            }
            m1 = d1;
        }
        float w1 = expf(d1 - m1);
        s1 += w1;
#pragma unroll
        for (int q = 0; q < 4; ++q) {
            ctx1[q].x += w1 * ev1[q].x; ctx1[q].y += w1 * ev1[q].y;
            ctx1[q].z += w1 * ev1[q].z; ctx1[q].w += w1 * ev1[q].w;
        }
    }

    float* pb0 = part + ((size_t)lc * B + b0) * PSTRIDE;
    float* pb1 = part + ((size_t)lc * B + b1) * PSTRIDE;
#pragma unroll
    for (int q = 0; q < 4; ++q) {
        *(float4*)(pb0 + q * 256 + lane * 4) = ctx0[q];
        *(float4*)(pb1 + q * 256 + lane * 4) = ctx1[q];
    }
    if (lane == 0) {
        pb0[1024] = m0; pb0[1025] = s0;
        pb1[1024] = m1; pb1[1025] = s1;
    }
}

// ---------------- merge partials -> ctx (bf16 pack) + attn output normalize
// Two-pass over 128 chunks (no scl array).
__global__ void k_attn_combine(const float* __restrict__ part,
                               const float* __restrict__ energy,
                               __bf16* __restrict__ catb, float* __restrict__ attn)
{
    int b = blockIdx.x, t = threadIdx.x;
    float m = -INFINITY;
    for (int c = 0; c < NLCHUNK; ++c)
        m = fmaxf(m, part[((size_t)c * B + b) * PSTRIDE + 1024]);
    float s = 0.f;
    float4 v = make_float4(0.f, 0.f, 0.f, 0.f);
    for (int c = 0; c < NLCHUNK; ++c) {
        const float* pb = part + ((size_t)c * B + b) * PSTRIDE;
        float scl = expf(pb[1024] - m);
        s += pb[1025] * scl;
        float4 p = *(const float4*)(pb + t * 4);
        v.x += p.x * scl; v.y += p.y * scl; v.z += p.z * scl; v.w += p.w * scl;
    }
    float inv = 1.f / s;
    v.x *= inv; v.y *= inv; v.z *= inv; v.w *= inv;
    int k = 1024 + t * 4;                                   // ctx k index
    __bf16* cp = catb + (size_t)(k >> 3) * 512 + b * 8 + (k & 7);
    cp[0] = (__bf16)v.x; cp[1] = (__bf16)v.y;
    cp[2] = (__bf16)v.z; cp[3] = (__bf16)v.w;

#pragma unroll
    for (int j = 0; j < 8; ++j) {
        int l = t + j * 256;
        attn[(size_t)b * Lw + l] = expf(energy[(size_t)b * Lw + l] - m) * inv;
    }
}

// ---------------- concat_out via bf16 MFMA, K-split over 8 waves (LDS reduce)
__global__ void k_concat_mfma(const __bf16* __restrict__ catb,
                              const float* __restrict__ W, const float* __restrict__ bias,
                              __bf16* __restrict__ conc)
{
    __shared__ float lds[8][64][20];
    int wave = threadIdx.x >> 6, lane = threadIdx.x & 63;
    int n0 = blockIdx.x * 16;
    int nl = n0 + (lane & 15);
    int kq = lane >> 4;
    int kbase = wave * 256;            // 8 waves x 256 = K=2048

    const float* wp = W + (size_t)nl * (2 * Hd) + kbase + kq * 8;
    const __bf16* ap = catb + (lane & 15) * 8;

    f32x4 acc[4] = {{0.f,0.f,0.f,0.f},{0.f,0.f,0.f,0.f},
                    {0.f,0.f,0.f,0.f},{0.f,0.f,0.f,0.f}};

#pragma unroll 4
    for (int k0 = 0; k0 < 256; k0 += 32) {
        float4 w0 = *(const float4*)(wp + k0);
        float4 w1 = *(const float4*)(wp + k0 + 4);
        bf16x8 bf; CVT8(bf, w0, w1);
        int kb = ((kbase + k0) >> 3) + kq;
#pragma unroll
        for (int mt = 0; mt < 4; ++mt) {
            bf16x8 a = *(const bf16x8*)(ap + (size_t)kb * 512 + mt * 128);
            acc[mt] = __builtin_amdgcn_mfma_f32_16x16x32_bf16(a, bf, acc[mt], 0, 0, 0);
        }
    }

#pragma unroll
    for (int mt = 0; mt < 4; ++mt)
        *(f32x4*)&lds[wave][lane][mt * 4] = acc[mt];
    __syncthreads();

    if (wave < 4) {
        int mt = wave;
        float bv = bias[nl];
#pragma unroll
        for (int r = 0; r < 4; ++r) {
            float s = 0.f;
#pragma unroll
            for (int w = 0; w < 8; ++w) s += lds[w][lane][mt * 4 + r];
            int m = mt * 16 + kq * 4 + r;       // batch
            conc[(size_t)(nl >> 3) * 512 + m * 8 + (nl & 7)] = (__bf16)tanhf(s + bv);
        }
    }
}

// ---------------- vocab projection via bf16 MFMA 16x16x32
__global__ void k_vocab_mfma(const __bf16* __restrict__ apack,
                             const float* __restrict__ W,
                             const float* __restrict__ bias,
                             float* __restrict__ out)
{
    int wave = threadIdx.x >> 6;
    int lane = threadIdx.x & 63;
    int n0 = (blockIdx.x * 2 + wave) * 16;
    if (n0 > Vd - 16) n0 = Vd - 16;        // tail shift-down (dup writes benign)

    int nl = n0 + (lane & 15);
    int kq = lane >> 4;
    const float* wp = W + (size_t)nl * Hd + kq * 8;
    const __bf16* ap = apack + (size_t)(lane & 15) * 8;

    f32x4 acc[4] = {{0.f,0.f,0.f,0.f},{0.f,0.f,0.f,0.f},
                    {0.f,0.f,0.f,0.f},{0.f,0.f,0.f,0.f}};

    float4 c0 = *(const float4*)(wp + 0);
    float4 c1 = *(const float4*)(wp + 4);
    float4 c2 = *(const float4*)(wp + 32);
    float4 c3 = *(const float4*)(wp + 36);

#pragma unroll 2
    for (int k0 = 0; k0 < Hd; k0 += 64) {
        int kn = (k0 + 64 < Hd) ? (k0 + 64) : k0;      // clamp: last prefetch unused
        float4 p0 = *(const float4*)(wp + kn);
        float4 p1 = *(const float4*)(wp + kn + 4);
        float4 p2 = *(const float4*)(wp + kn + 32);
        float4 p3 = *(const float4*)(wp + kn + 36);

        bf16x8 bf0; CVT8(bf0, c0, c1);
        bf16x8 bf1; CVT8(bf1, c2, c3);
        int kb0 = (k0 >> 3) + kq, kb1 = kb0 + 4;
#pragma unroll
        for (int mt = 0; mt < 4; ++mt) {
            bf16x8 a0 = *(const bf16x8*)(ap + (size_t)kb0 * 512 + mt * 128);
            acc[mt] = __builtin_amdgcn_mfma_f32_16x16x32_bf16(a0, bf0, acc[mt], 0, 0, 0);
        }
#pragma unroll
        for (int mt = 0; mt < 4; ++mt) {
            bf16x8 a1 = *(const bf16x8*)(ap + (size_t)kb1 * 512 + mt * 128);
            acc[mt] = __builtin_amdgcn_mfma_f32_16x16x32_bf16(a1, bf1, acc[mt], 0, 0, 0);
        }
        c0 = p0; c1 = p1; c2 = p2; c3 = p3;
    }

    float bv = bias[nl];
#pragma unroll
    for (int mt = 0; mt < 4; ++mt)
#pragma unroll
        for (int r = 0; r < 4; ++r) {
            int m = mt * 16 + (lane >> 4) * 4 + r;   // batch (C/D row)
            out[(size_t)m * Vd + nl] = acc[mt][r] + bv;
        }
}

extern "C" void kernel_launch(void* const* d_in, const int* in_sizes, int n_in,
                              void* d_out, int out_size, void* d_ws, size_t ws_size,
                              hipStream_t stream)
{
    const int*   seq    = (const int*)d_in[0];
    const float* enc    = (const float*)d_in[1];
    const float* h0     = (const float*)d_in[2];
    const float* c0     = (const float*)d_in[3];
    const float* emb    = (const float*)d_in[4];
    const float* W_ih   = (const float*)d_in[5];
    const float* W_hh   = (const float*)d_in[6];
    const float* b_ih   = (const float*)d_in[7];
    const float* b_hh   = (const float*)d_in[8];
    const float* W_cat  = (const float*)d_in[9];
    const float* b_cat  = (const float*)d_in[10];
    const float* W_out  = (const float*)d_in[11];
    const float* b_out  = (const float*)d_in[12];
    float* out = (float*)d_out;
    float* ws  = (float*)d_ws;

    __bf16* catb   = (__bf16*)(ws + WS_CATB);
    float*  energy = ws + WS_ENERGY;
    float*  part   = ws + WS_PART;
    __bf16* conc   = (__bf16*)(ws + WS_CONC);

    // fused embed+gates+LSTM: 256 blocks (4 hh each) x 512 threads
    k_gates_lstm<<<256, 512, 0, stream>>>(seq, emb, h0, W_ih, W_hh, b_ih, b_hh, c0,
                                          out + OUT_H1, out + OUT_C1, catb);
    // energies + partials, b-contiguous: (128 lchunks x 4 bgroups) x 512 threads
    k_attn_part<<<dim3(NLCHUNK, B / BGRP), 512, 0, stream>>>(enc, out + OUT_H1,
                                                             energy, part);
    // merge partials + attn normalize: 64 blocks x 256 threads
    k_attn_combine<<<B, 256, 0, stream>>>(part, energy, catb, out + OUT_ATTN);
    // concat: 64 blocks x 512 threads (8-way K-split)
    k_concat_mfma<<<64, 512, 0, stream>>>(catb, W_cat, b_cat, conc);
    // vocab: 1571 blocks x 128 threads
    k_vocab_mfma<<<1571, 128, 0, stream>>>(conc, W_out, b_out, out);
}

// Round 15
// 215.076 us; speedup vs baseline: 1.6951x; 1.2048x over previous
//
#include <hip/hip_runtime.h>
#include <math.h>

#define B 64
#define Lw 2048
#define Hd 1024
#define Vd 50257

// ws offsets (in floats)
#define WS_CATB   0          // bf16 pack [256][64][8]: h1(kb 0..127), ctx(128..255) = 65536 f
#define WS_ENERGY 65536      // energies [64][2048] = 131072
#define WS_PART   196608     // 32*64 partials * 1032 = 2113536
#define WS_CONC   2310144    // concat_out bf16 pack [128][64][8] = 32768 f

// d_out offsets (floats): output[B][V], h1[1][B][H], c1[1][B][H], attn[B][1][L]
#define OUT_H1   3216448
#define OUT_C1   3281984
#define OUT_ATTN 3347520

#define NCHUNK 32
#define LCHUNK 64
#define PSTRIDE 1032

typedef __bf16 bf16x8 __attribute__((ext_vector_type(8)));
typedef float f32x4 __attribute__((ext_vector_type(4)));

__device__ __forceinline__ float sigm(float x) { return 1.f / (1.f + expf(-x)); }

// Non-temporal float4 load (gfx950 'nt' flag): no L3 allocation, so streaming
// single-use data does not evict the harness's dirty poison lines (which would
// force ~256MB of writeback traffic against our cold reads every replay).
__device__ __forceinline__ float4 ntload4(const float* p)
{
    f32x4 v = __builtin_nontemporal_load((const f32x4*)p);
    return make_float4(v[0], v[1], v[2], v[3]);
}

#define CVT8(dst, w0, w1)                                            \
    dst[0] = (__bf16)w0.x; dst[1] = (__bf16)w0.y;                    \
    dst[2] = (__bf16)w0.z; dst[3] = (__bf16)w0.w;                    \
    dst[4] = (__bf16)w1.x; dst[5] = (__bf16)w1.y;                    \
    dst[6] = (__bf16)w1.z; dst[7] = (__bf16)w1.w;

// ---------------- fused embed + gates(MFMA, 8-wave K-split) + LSTM pointwise
__global__ void k_gates_lstm(const int* __restrict__ seq,
                             const float* __restrict__ emb, const float* __restrict__ h0,
                             const float* __restrict__ W_ih, const float* __restrict__ W_hh,
                             const float* __restrict__ b_ih, const float* __restrict__ b_hh,
                             const float* __restrict__ c0,
                             float* __restrict__ h1o, float* __restrict__ c1o,
                             __bf16* __restrict__ catb)
{
    __shared__ float lds[8][64][20];
    __shared__ float gsum[16][66];

    int wave = threadIdx.x >> 6, lane = threadIdx.x & 63;
    int hh0 = blockIdx.x * 4;
    int rloc = lane & 15;                      // local row: gate g, hh offset
    int wrow = (rloc >> 2) * Hd + hh0 + (rloc & 3);
    int kq = lane >> 4;
    int isH = wave >> 2;
    int kbase = (wave & 3) * 256;

    const float* wp = (isH ? W_hh : W_ih) + (size_t)wrow * Hd + kbase + kq * 8;

    f32x4 acc[4] = {{0.f,0.f,0.f,0.f},{0.f,0.f,0.f,0.f},
                    {0.f,0.f,0.f,0.f},{0.f,0.f,0.f,0.f}};

    if (!isH) {
        int tok[4];
#pragma unroll
        for (int mt = 0; mt < 4; ++mt) tok[mt] = seq[mt * 16 + rloc];
#pragma unroll 2
        for (int k0 = 0; k0 < 256; k0 += 32) {
            float4 w0 = ntload4(wp + k0);          // W read once -> nt
            float4 w1 = ntload4(wp + k0 + 4);
            bf16x8 bf; CVT8(bf, w0, w1);
#pragma unroll
            for (int mt = 0; mt < 4; ++mt) {
                const float* xp = emb + (size_t)tok[mt] * Hd + kbase + k0 + kq * 8;
                float4 a0 = *(const float4*)xp;    // emb rows reused -> cached
                float4 a1 = *(const float4*)(xp + 4);
                bf16x8 af; CVT8(af, a0, a1);
                acc[mt] = __builtin_amdgcn_mfma_f32_16x16x32_bf16(af, bf, acc[mt], 0, 0, 0);
            }
        }
    } else {
#pragma unroll 2
        for (int k0 = 0; k0 < 256; k0 += 32) {
            float4 w0 = ntload4(wp + k0);
            float4 w1 = ntload4(wp + k0 + 4);
            bf16x8 bhi, blo;
            {
                float wf[8] = {w0.x, w0.y, w0.z, w0.w, w1.x, w1.y, w1.z, w1.w};
#pragma unroll
                for (int i = 0; i < 8; ++i) {
                    __bf16 hi = (__bf16)wf[i];
                    bhi[i] = hi;
                    blo[i] = (__bf16)(wf[i] - (float)hi);
                }
            }
#pragma unroll
            for (int mt = 0; mt < 4; ++mt) {
                const float* hp = h0 + (size_t)(mt * 16 + rloc) * Hd + kbase + k0 + kq * 8;
                float4 a0 = *(const float4*)hp;    // h0 small -> cached
                float4 a1 = *(const float4*)(hp + 4);
                float hf[8] = {a0.x, a0.y, a0.z, a0.w, a1.x, a1.y, a1.z, a1.w};
                bf16x8 ahi, alo;
#pragma unroll
                for (int i = 0; i < 8; ++i) {
                    __bf16 hi = (__bf16)hf[i];
                    ahi[i] = hi;
                    alo[i] = (__bf16)(hf[i] - (float)hi);
                }
                acc[mt] = __builtin_amdgcn_mfma_f32_16x16x32_bf16(ahi, bhi, acc[mt], 0, 0, 0);
                acc[mt] = __builtin_amdgcn_mfma_f32_16x16x32_bf16(ahi, blo, acc[mt], 0, 0, 0);
                acc[mt] = __builtin_amdgcn_mfma_f32_16x16x32_bf16(alo, bhi, acc[mt], 0, 0, 0);
            }
        }
    }

#pragma unroll
    for (int mt = 0; mt < 4; ++mt)
        *(f32x4*)&lds[wave][lane][mt * 4] = acc[mt];
    __syncthreads();

    if (wave < 4) {
        int mt = wave;
        float bv = b_ih[wrow] + b_hh[wrow];
#pragma unroll
        for (int r = 0; r < 4; ++r) {
            float s = 0.f;
#pragma unroll
            for (int w = 0; w < 8; ++w) s += lds[w][lane][mt * 4 + r];
            int m = mt * 16 + kq * 4 + r;       // batch
            gsum[rloc][m] = s + bv;
        }
    }
    __syncthreads();

    int t = threadIdx.x;
    if (t < 256) {
        int b = t & 63, hl = t >> 6;
        int hh = hh0 + hl;
        float gi = gsum[0 + hl][b];
        float gf = gsum[4 + hl][b];
        float gg = gsum[8 + hl][b];
        float go = gsum[12 + hl][b];
        float c  = c0[(size_t)b * Hd + hh];
        float c1 = sigm(gf) * c + sigm(gi) * tanhf(gg);
        float h1 = sigm(go) * tanhf(c1);
        h1o[(size_t)b * Hd + hh] = h1;
        c1o[(size_t)b * Hd + hh] = c1;
        catb[(size_t)(hh >> 3) * 512 + b * 8 + (hh & 7)] = (__bf16)h1;
    }
}

// ---------------- fused energies + online-softmax context partials (one enc pass)
// r11-proven structure; enc loads non-temporal (single-use stream).
__global__ void k_attn_part(const float* __restrict__ enc, const float* __restrict__ h1,
                            float* __restrict__ energy, float* __restrict__ part)
{
    int chunk = blockIdx.x, b = blockIdx.y;
    int wave = threadIdx.x >> 6, lane = threadIdx.x & 63;

    float4 qv[4], ctx[4];
#pragma unroll
    for (int q = 0; q < 4; ++q) {
        qv[q] = *(const float4*)(h1 + (size_t)b * Hd + q * 256 + lane * 4);
        ctx[q] = make_float4(0.f, 0.f, 0.f, 0.f);
    }
    float m = -INFINITY, s = 0.f;

    for (int i = 0; i < LCHUNK / 8; ++i) {
        int l = chunk * LCHUNK + i * 8 + wave * 2;
        const float* ep0 = enc + ((size_t)l * B + b) * Hd + lane * 4;
        const float* ep1 = ep0 + (size_t)B * Hd;
        float4 ev0[4], ev1[4];
#pragma unroll
        for (int q = 0; q < 4; ++q) {
            ev0[q] = ntload4(ep0 + q * 256);
            ev1[q] = ntload4(ep1 + q * 256);
        }
        float d0 = 0.f, d1 = 0.f;
#pragma unroll
        for (int q = 0; q < 4; ++q) {
            d0 += ev0[q].x * qv[q].x + ev0[q].y * qv[q].y
                + ev0[q].z * qv[q].z + ev0[q].w * qv[q].w;
            d1 += ev1[q].x * qv[q].x + ev1[q].y * qv[q].y
                + ev1[q].z * qv[q].z + ev1[q].w * qv[q].w;
        }
#pragma unroll
        for (int off = 32; off >= 1; off >>= 1) {
            d0 += __shfl_xor(d0, off);
            d1 += __shfl_xor(d1, off);
        }
        if (lane == 0) {
            energy[(size_t)b * Lw + l] = d0;
            energy[(size_t)b * Lw + l + 1] = d1;
        }

        float mn = fmaxf(d0, d1);
        if (mn > m) {                          // wave-uniform
            float sc = expf(m - mn);
            s *= sc;
#pragma unroll
            for (int q = 0; q < 4; ++q) {
                ctx[q].x *= sc; ctx[q].y *= sc; ctx[q].z *= sc; ctx[q].w *= sc;
            }
            m = mn;
        }
        float w0 = expf(d0 - m), w1 = expf(d1 - m);
        s += w0 + w1;
#pragma unroll
        for (int q = 0; q < 4; ++q) {
            ctx[q].x += w0 * ev0[q].x + w1 * ev1[q].x;
            ctx[q].y += w0 * ev0[q].y + w1 * ev1[q].y;
            ctx[q].z += w0 * ev0[q].z + w1 * ev1[q].z;
            ctx[q].w += w0 * ev0[q].w + w1 * ev1[q].w;
        }
    }

    // combine the 4 waves of this block
    __shared__ float lctx[4][Hd];
    __shared__ float lms[4][2];
#pragma unroll
    for (int q = 0; q < 4; ++q)
        *(float4*)(&lctx[wave][q * 256 + lane * 4]) = ctx[q];
    if (lane == 0) { lms[wave][0] = m; lms[wave][1] = s; }
    __syncthreads();

    float mb = fmaxf(fmaxf(lms[0][0], lms[1][0]), fmaxf(lms[2][0], lms[3][0]));
    float sc0 = expf(lms[0][0] - mb), sc1 = expf(lms[1][0] - mb);
    float sc2 = expf(lms[2][0] - mb), sc3 = expf(lms[3][0] - mb);
    float sb = lms[0][1] * sc0 + lms[1][1] * sc1 + lms[2][1] * sc2 + lms[3][1] * sc3;

    int t = threadIdx.x;
    float* pb = part + (size_t)(chunk * B + b) * PSTRIDE;
    float4 a0 = *(float4*)(&lctx[0][t * 4]);
    float4 a1 = *(float4*)(&lctx[1][t * 4]);
    float4 a2 = *(float4*)(&lctx[2][t * 4]);
    float4 a3 = *(float4*)(&lctx[3][t * 4]);
    float4 v;
    v.x = a0.x * sc0 + a1.x * sc1 + a2.x * sc2 + a3.x * sc3;
    v.y = a0.y * sc0 + a1.y * sc1 + a2.y * sc2 + a3.y * sc3;
    v.z = a0.z * sc0 + a1.z * sc1 + a2.z * sc2 + a3.z * sc3;
    v.w = a0.w * sc0 + a1.w * sc1 + a2.w * sc2 + a3.w * sc3;
    *(float4*)(pb + t * 4) = v;
    if (t == 0) { pb[1024] = mb; pb[1025] = sb; }
}

// ---------------- merge partials -> ctx (bf16 pack) + attn output normalize
__global__ void k_attn_combine(const float* __restrict__ part,
                               const float* __restrict__ energy,
                               __bf16* __restrict__ catb, float* __restrict__ attn)
{
    int b = blockIdx.x, t = threadIdx.x;
    float m = -INFINITY;
#pragma unroll
    for (int c = 0; c < NCHUNK; ++c)
        m = fmaxf(m, part[(size_t)(c * B + b) * PSTRIDE + 1024]);
    float s = 0.f, scl[NCHUNK];
#pragma unroll
    for (int c = 0; c < NCHUNK; ++c) {
        const float* pb = part + (size_t)(c * B + b) * PSTRIDE;
        scl[c] = expf(pb[1024] - m);
        s += pb[1025] * scl[c];
    }
    float4 v = make_float4(0.f, 0.f, 0.f, 0.f);
#pragma unroll
    for (int c = 0; c < NCHUNK; ++c) {
        float4 p = *(const float4*)(part + (size_t)(c * B + b) * PSTRIDE + t * 4);
        v.x += p.x * scl[c]; v.y += p.y * scl[c]; v.z += p.z * scl[c]; v.w += p.w * scl[c];
    }
    float inv = 1.f / s;
    v.x *= inv; v.y *= inv; v.z *= inv; v.w *= inv;
    int k = 1024 + t * 4;                                   // ctx k index
    __bf16* cp = catb + (size_t)(k >> 3) * 512 + b * 8 + (k & 7);
    cp[0] = (__bf16)v.x; cp[1] = (__bf16)v.y;
    cp[2] = (__bf16)v.z; cp[3] = (__bf16)v.w;

#pragma unroll
    for (int j = 0; j < 8; ++j) {
        int l = t + j * 256;
        attn[(size_t)b * Lw + l] = expf(energy[(size_t)b * Lw + l] - m) * inv;
    }
}

// ---------------- concat_out via bf16 MFMA, K-split over 8 waves (LDS reduce)
__global__ void k_concat_mfma(const __bf16* __restrict__ catb,
                              const float* __restrict__ W, const float* __restrict__ bias,
                              __bf16* __restrict__ conc)
{
    __shared__ float lds[8][64][20];
    int wave = threadIdx.x >> 6, lane = threadIdx.x & 63;
    int n0 = blockIdx.x * 16;
    int nl = n0 + (lane & 15);
    int kq = lane >> 4;
    int kbase = wave * 256;            // 8 waves x 256 = K=2048

    const float* wp = W + (size_t)nl * (2 * Hd) + kbase + kq * 8;
    const __bf16* ap = catb + (lane & 15) * 8;

    f32x4 acc[4] = {{0.f,0.f,0.f,0.f},{0.f,0.f,0.f,0.f},
                    {0.f,0.f,0.f,0.f},{0.f,0.f,0.f,0.f}};

#pragma unroll 4
    for (int k0 = 0; k0 < 256; k0 += 32) {
        float4 w0 = ntload4(wp + k0);
        float4 w1 = ntload4(wp + k0 + 4);
        bf16x8 bf; CVT8(bf, w0, w1);
        int kb = ((kbase + k0) >> 3) + kq;
#pragma unroll
        for (int mt = 0; mt < 4; ++mt) {
            bf16x8 a = *(const bf16x8*)(ap + (size_t)kb * 512 + mt * 128);
            acc[mt] = __builtin_amdgcn_mfma_f32_16x16x32_bf16(a, bf, acc[mt], 0, 0, 0);
        }
    }

#pragma unroll
    for (int mt = 0; mt < 4; ++mt)
        *(f32x4*)&lds[wave][lane][mt * 4] = acc[mt];
    __syncthreads();

    if (wave < 4) {
        int mt = wave;
        float bv = bias[nl];
#pragma unroll
        for (int r = 0; r < 4; ++r) {
            float s = 0.f;
#pragma unroll
            for (int w = 0; w < 8; ++w) s += lds[w][lane][mt * 4 + r];
            int m = mt * 16 + kq * 4 + r;       // batch
            conc[(size_t)(nl >> 3) * 512 + m * 8 + (nl & 7)] = (__bf16)tanhf(s + bv);
        }
    }
}

// ---------------- vocab projection via bf16 MFMA 16x16x32
// k-step 64 + register double-buffer; W loads non-temporal (206MB single-use).
__global__ void k_vocab_mfma(const __bf16* __restrict__ apack,
                             const float* __restrict__ W,
                             const float* __restrict__ bias,
                             float* __restrict__ out)
{
    int wave = threadIdx.x >> 6;
    int lane = threadIdx.x & 63;
    int n0 = (blockIdx.x * 2 + wave) * 16;
    if (n0 > Vd - 16) n0 = Vd - 16;        // tail shift-down (dup writes benign)

    int nl = n0 + (lane & 15);
    int kq = lane >> 4;
    const float* wp = W + (size_t)nl * Hd + kq * 8;
    const __bf16* ap = apack + (size_t)(lane & 15) * 8;

    f32x4 acc[4] = {{0.f,0.f,0.f,0.f},{0.f,0.f,0.f,0.f},
                    {0.f,0.f,0.f,0.f},{0.f,0.f,0.f,0.f}};

    float4 c0 = ntload4(wp + 0);
    float4 c1 = ntload4(wp + 4);
    float4 c2 = ntload4(wp + 32);
    float4 c3 = ntload4(wp + 36);

#pragma unroll 2
    for (int k0 = 0; k0 < Hd; k0 += 64) {
        int kn = (k0 + 64 < Hd) ? (k0 + 64) : k0;      // clamp: last prefetch unused
        float4 p0 = ntload4(wp + kn);
        float4 p1 = ntload4(wp + kn + 4);
        float4 p2 = ntload4(wp + kn + 32);
        float4 p3 = ntload4(wp + kn + 36);

        bf16x8 bf0; CVT8(bf0, c0, c1);
        bf16x8 bf1; CVT8(bf1, c2, c3);
        int kb0 = (k0 >> 3) + kq, kb1 = kb0 + 4;
#pragma unroll
        for (int mt = 0; mt < 4; ++mt) {
            bf16x8 a0 = *(const bf16x8*)(ap + (size_t)kb0 * 512 + mt * 128);
            acc[mt] = __builtin_amdgcn_mfma_f32_16x16x32_bf16(a0, bf0, acc[mt], 0, 0, 0);
        }
#pragma unroll
        for (int mt = 0; mt < 4; ++mt) {
            bf16x8 a1 = *(const bf16x8*)(ap + (size_t)kb1 * 512 + mt * 128);
            acc[mt] = __builtin_amdgcn_mfma_f32_16x16x32_bf16(a1, bf1, acc[mt], 0, 0, 0);
        }
        c0 = p0; c1 = p1; c2 = p2; c3 = p3;
    }

    float bv = bias[nl];
#pragma unroll
    for (int mt = 0; mt < 4; ++mt)
#pragma unroll
        for (int r = 0; r < 4; ++r) {
            int m = mt * 16 + (lane >> 4) * 4 + r;   // batch (C/D row)
            out[(size_t)m * Vd + nl] = acc[mt][r] + bv;
        }
}

extern "C" void kernel_launch(void* const* d_in, const int* in_sizes, int n_in,
                              void* d_out, int out_size, void* d_ws, size_t ws_size,
                              hipStream_t stream)
{
    const int*   seq    = (const int*)d_in[0];
    const float* enc    = (const float*)d_in[1];
    const float* h0     = (const float*)d_in[2];
    const float* c0     = (const float*)d_in[3];
    const float* emb    = (const float*)d_in[4];
    const float* W_ih   = (const float*)d_in[5];
    const float* W_hh   = (const float*)d_in[6];
    const float* b_ih   = (const float*)d_in[7];
    const float* b_hh   = (const float*)d_in[8];
    const float* W_cat  = (const float*)d_in[9];
    const float* b_cat  = (const float*)d_in[10];
    const float* W_out  = (const float*)d_in[11];
    const float* b_out  = (const float*)d_in[12];
    float* out = (float*)d_out;
    float* ws  = (float*)d_ws;

    __bf16* catb   = (__bf16*)(ws + WS_CATB);
    float*  energy = ws + WS_ENERGY;
    float*  part   = ws + WS_PART;
    __bf16* conc   = (__bf16*)(ws + WS_CONC);

    // fused embed+gates+LSTM: 256 blocks (4 hh each) x 512 threads
    k_gates_lstm<<<256, 512, 0, stream>>>(seq, emb, h0, W_ih, W_hh, b_ih, b_hh, c0,
                                          out + OUT_H1, out + OUT_C1, catb);
    // energies + online-softmax partials: 32x64 blocks x 256 threads
    k_attn_part<<<dim3(NCHUNK, B), 256, 0, stream>>>(enc, out + OUT_H1, energy, part);
    // merge partials + attn normalize: 64 blocks x 256 threads
    k_attn_combine<<<B, 256, 0, stream>>>(part, energy, catb, out + OUT_ATTN);
    // concat: 64 blocks x 512 threads (8-way K-split)
    k_concat_mfma<<<64, 512, 0, stream>>>(catb, W_cat, b_cat, conc);
    // vocab: 1571 blocks x 128 threads
    k_vocab_mfma<<<1571, 128, 0, stream>>>(conc, W_out, b_out, out);
}